// Round 7
// baseline (142.865 us; speedup 1.0000x reference)
//
#include <hip/hip_runtime.h>
#include <math.h>

#define Bb 4
#define Tt 512
#define Uu 128
#define Hh 512
#define Vv 41

typedef __attribute__((ext_vector_type(8))) short short8;
typedef __attribute__((ext_vector_type(4))) float f32x4;
typedef __attribute__((ext_vector_type(2))) float v2f;

// RNE bf16 pack of two floats -> u32 [lo | hi<<16]
__device__ __forceinline__ unsigned pack_bf16_rne(float hi, float lo) {
    unsigned xh = __float_as_uint(hi); xh += 0x7fffu + ((xh >> 16) & 1u);
    unsigned xl = __float_as_uint(lo); xl += 0x7fffu + ((xl >> 16) & 1u);
    return __builtin_amdgcn_perm(xh, xl, 0x07060302);
}

__device__ __forceinline__ unsigned short bf16_rne(float v) {
    unsigned x = __float_as_uint(v);
    x += 0x7fffu + ((x >> 16) & 1u);
    return (unsigned short)(x >> 16);
}

// bf16 pair unpack (u32 = [lo | hi<<16])
__device__ __forceinline__ float bf16lo(unsigned u) { return __uint_as_float(u << 16); }
__device__ __forceinline__ float bf16hi(unsigned u) { return __uint_as_float(u & 0xffff0000u); }

// tanh approx: med3-clamp to [-3,3], odd minimax quintic in t=x^2 (max err ~0.024).
__device__ __forceinline__ unsigned tanh2_pack(float x0, float x1) {
    v2f xc;
    xc.x = __builtin_amdgcn_fmed3f(x0, -3.0f, 3.0f);
    xc.y = __builtin_amdgcn_fmed3f(x1, -3.0f, 3.0f);
    v2f t = xc * xc;
    v2f p = t * (v2f){-0.00140725f, -0.00140725f} + (v2f){0.0288922f, 0.0288922f};
    p = p * t + (v2f){-0.2177528f, -0.2177528f};
    p = p * t + (v2f){0.9707868f, 0.9707868f};
    v2f g = xc * p;
    return __builtin_amdgcn_perm(__float_as_uint(g.y), __float_as_uint(g.x), 0x07060302);
}

// -------- Prep: blocks 0..135: W1,W2,Wl -> MFMA B-frag order
// Wp[ntile][kstep][lane][8 bf16]; block 135 also writes lengths.
// Blocks 136..167: tgt -> A-frag order tgtA[rowtile][kstep][lane][8 bf16].
__global__ __launch_bounds__(256) void prep_pack(
    const float* __restrict__ W1, const float* __restrict__ W2,
    const float* __restrict__ Wl, const float* __restrict__ tgt,
    unsigned short* __restrict__ Wp1, unsigned short* __restrict__ Wp2,
    unsigned short* __restrict__ Wpl, unsigned short* __restrict__ tgtA,
    const int* __restrict__ sl, const int* __restrict__ tl,
    float* __restrict__ lenDst)
{
    __shared__ __align__(16) char smem[16640];
    const int bid = blockIdx.x, tid = threadIdx.x;

    if (bid >= 136) {   // ---- tgt -> A-frag pack
        unsigned short (*At)[520] = (unsigned short (*)[520])smem;
        const int rt = bid - 136;
        const float4* t4 = (const float4*)(tgt + (size_t)rt * 16 * Hh);
        #pragma unroll
        for (int j = 0; j < 8; ++j) {
            int fi = j * 256 + tid;            // 0..2047
            int row = fi >> 7, c4 = fi & 127;
            float4 v = t4[fi];
            uint2 pk;
            pk.x = pack_bf16_rne(v.y, v.x);
            pk.y = pack_bf16_rne(v.w, v.z);
            *(uint2*)&At[row][c4 * 4] = pk;
        }
        __syncthreads();
        #pragma unroll
        for (int i = 0; i < 4; ++i) {
            int chunk = i * 256 + tid;         // 0..1023
            int ks = chunk >> 6, l = chunk & 63;
            int q = l >> 4, nc = l & 15;
            short8 v = *(const short8*)&At[nc][ks * 32 + q * 8];
            *(short8*)(tgtA + ((size_t)(rt * 16 + ks) * 64 + l) * 8) = v;
        }
        return;
    }

    if (bid == 135 && tid < 2 * Bb)
        lenDst[tid] = (tid < Bb) ? (float)sl[tid] : (float)tl[tid - Bb];

    float (*T)[65] = (float (*)[65])smem;
    const float* Wsrc; unsigned short* Wdst; int k0, n0, isWl;
    if (bid < 64)       { Wsrc = W1; Wdst = Wp1; k0 = (bid >> 3) * 64; n0 = (bid & 7) * 64; isWl = 0; }
    else if (bid < 128) { Wsrc = W2; Wdst = Wp2; k0 = ((bid - 64) >> 3) * 64; n0 = ((bid - 64) & 7) * 64; isWl = 0; }
    else                { Wsrc = Wl; Wdst = Wpl; k0 = (bid - 128) * 64; n0 = 0; isWl = 1; }

    #pragma unroll
    for (int i = 0; i < 16; ++i) {
        int idx = i * 256 + tid;
        int kk = idx >> 6, nn = idx & 63;
        float v;
        if (isWl) v = (nn < Vv) ? Wl[(k0 + kk) * Vv + nn] : 0.0f;
        else      v = Wsrc[(size_t)(k0 + kk) * 512 + n0 + nn];
        T[kk][nn] = v;
    }
    __syncthreads();

    #pragma unroll
    for (int i = 0; i < 2; ++i) {
        int task = i * 256 + tid;
        int nn = task & 63, kg = task >> 6;
        if (isWl && nn >= 48) continue;
        int n = n0 + nn, k = k0 + kg * 8;
        float e[8];
        #pragma unroll
        for (int j = 0; j < 8; ++j) e[j] = T[kg * 8 + j][nn];
        uint4 pk;
        pk.x = pack_bf16_rne(e[1], e[0]);
        pk.y = pack_bf16_rne(e[3], e[2]);
        pk.z = pack_bf16_rne(e[5], e[4]);
        pk.w = pack_bf16_rne(e[7], e[6]);
        int ntg = n >> 4, ncol = n & 15;
        int ks = (k >> 5) & 15, quad = (k >> 3) & 3;
        int lane = quad * 16 + ncol;
        *(uint4*)(Wdst + (size_t)((ntg * 16 + ks) * 64 + lane) * 8) = pk;
    }
}

// -------- T1: h1 = gelu(tgt@W1 + b1) -> h1A (A-frag order).
__global__ __launch_bounds__(128) void gemm_t1(
    const unsigned short* __restrict__ tgtA,
    const unsigned short* __restrict__ Wp1, const float* __restrict__ b1,
    unsigned short* __restrict__ h1A)
{
    __shared__ unsigned short At[16][72];
    const int nb = blockIdx.x, rt = blockIdx.y;
    const int tid = threadIdx.x, lane = tid & 63, w = tid >> 6;
    const int ncol = lane & 15, quad = lane >> 4;
    const int nt0 = nb * 4 + w * 2;

    const unsigned short* ap = tgtA + ((size_t)rt * 1024 + lane) * 8;
    const unsigned short* bp = Wp1 + (size_t)lane * 8;

    f32x4 acc0 = (f32x4){0.f,0.f,0.f,0.f}, acc1 = (f32x4){0.f,0.f,0.f,0.f};
    short8 ac  = *(const short8*)(ap);
    short8 b0c = *(const short8*)(bp + (size_t)nt0 * 8192);
    short8 b1c = *(const short8*)(bp + (size_t)(nt0 + 1) * 8192);

    #pragma unroll
    for (int ks = 0; ks < 16; ++ks) {
        short8 an, b0n, b1n;
        if (ks < 15) {
            an  = *(const short8*)(ap + (ks + 1) * 512);
            b0n = *(const short8*)(bp + (size_t)nt0 * 8192 + (ks + 1) * 512);
            b1n = *(const short8*)(bp + (size_t)(nt0 + 1) * 8192 + (ks + 1) * 512);
        }
        acc0 = __builtin_amdgcn_mfma_f32_16x16x32_bf16(ac, b0c, acc0, 0, 0, 0);
        acc1 = __builtin_amdgcn_mfma_f32_16x16x32_bf16(ac, b1c, acc1, 0, 0, 0);
        ac = an; b0c = b0n; b1c = b1n;
    }

    #pragma unroll
    for (int nt = 0; nt < 2; ++nt) {
        int n = nb * 64 + w * 32 + nt * 16 + ncol;
        float bias = b1[n];
        f32x4 A = nt ? acc1 : acc0;
        #pragma unroll
        for (int r = 0; r < 4; ++r) {
            float v = A[r] + bias;
            float g = 0.5f * v * (1.0f + erff(v * 0.70710678118654752f));
            At[quad * 4 + r][w * 32 + nt * 16 + ncol] = bf16_rne(g);
        }
    }
    __syncthreads();

    {
        int l = lane;
        short8 v = *(const short8*)&At[l & 15][w * 32 + (l >> 4) * 8];
        int ksg = nb * 2 + w;
        *(short8*)(h1A + ((size_t)(rt * 16 + ksg) * 64 + l) * 8) = v;
    }
}

// -------- T2+LN fused: h2 = h1@W2+b2; LN(h2) -> tgtPb bf16 A-frag layout
// tgtPb[b][k/8 (64)][u (128)][8 bf16].  32 blocks x 512 thr (8 waves, wave=64 n).
__global__ __launch_bounds__(512) void gemm_t2ln(
    const unsigned short* __restrict__ h1A,
    const unsigned short* __restrict__ Wp2, const float* __restrict__ b2,
    const float* __restrict__ ln_g, const float* __restrict__ ln_b,
    unsigned short* __restrict__ tgtPb)
{
    __shared__ float Ct[16][520];
    const int rt = blockIdx.x;
    const int tid = threadIdx.x, lane = tid & 63, w = tid >> 6;
    const int ncol = lane & 15, quad = lane >> 4;
    const int nt0 = w * 4;

    const unsigned short* ap = h1A + ((size_t)rt * 1024 + lane) * 8;
    const unsigned short* bp = Wp2 + (size_t)lane * 8 + (size_t)nt0 * 8192;

    f32x4 acc[4];
    #pragma unroll
    for (int i = 0; i < 4; ++i) acc[i] = (f32x4){0.f, 0.f, 0.f, 0.f};

    short8 ac = *(const short8*)(ap);
    short8 bc[4];
    #pragma unroll
    for (int i = 0; i < 4; ++i) bc[i] = *(const short8*)(bp + (size_t)i * 8192);

    #pragma unroll
    for (int ks = 0; ks < 16; ++ks) {
        short8 an, bn[4];
        if (ks < 15) {
            an = *(const short8*)(ap + (ks + 1) * 512);
            #pragma unroll
            for (int i = 0; i < 4; ++i)
                bn[i] = *(const short8*)(bp + (size_t)i * 8192 + (ks + 1) * 512);
        }
        #pragma unroll
        for (int i = 0; i < 4; ++i)
            acc[i] = __builtin_amdgcn_mfma_f32_16x16x32_bf16(ac, bc[i], acc[i], 0, 0, 0);
        ac = an;
        #pragma unroll
        for (int i = 0; i < 4; ++i) bc[i] = bn[i];
    }

    #pragma unroll
    for (int nt = 0; nt < 4; ++nt) {
        int n = w * 64 + nt * 16 + ncol;
        float bias = b2[n];
        #pragma unroll
        for (int r = 0; r < 4; ++r)
            Ct[quad * 4 + r][n] = acc[nt][r] + bias;
    }
    __syncthreads();

    // LayerNorm: wave w handles rows 2w, 2w+1; write bf16 A-frag layout
    #pragma unroll
    for (int rr = 0; rr < 2; ++rr) {
        const int row = w * 2 + rr;
        const float4* cr = (const float4*)&Ct[row][0];
        float4 v0 = cr[lane], v1 = cr[lane + 64];
        float s = v0.x + v0.y + v0.z + v0.w + v1.x + v1.y + v1.z + v1.w;
        float q = v0.x*v0.x + v0.y*v0.y + v0.z*v0.z + v0.w*v0.w
                + v1.x*v1.x + v1.y*v1.y + v1.z*v1.z + v1.w*v1.w;
        #pragma unroll
        for (int off = 32; off > 0; off >>= 1) {
            s += __shfl_xor(s, off, 64);
            q += __shfl_xor(q, off, 64);
        }
        float mu = s * (1.0f / Hh);
        float rs = rsqrtf(q * (1.0f / Hh) - mu * mu + 1e-5f);

        const int r = rt * 16 + row;
        const int bb = r >> 7, u = r & 127;
        #pragma unroll
        for (int j = 0; j < 2; ++j) {
            int k0 = j * 256 + lane * 4;       // this lane's 4 k-values
            float4 v = j ? v1 : v0;
            float4 g4 = ((const float4*)ln_g)[j * 64 + lane];
            float4 b4 = ((const float4*)ln_b)[j * 64 + lane];
            float4 o;
            o.x = (v.x - mu) * rs * g4.x + b4.x;
            o.y = (v.y - mu) * rs * g4.y + b4.y;
            o.z = (v.z - mu) * rs * g4.z + b4.z;
            o.w = (v.w - mu) * rs * g4.w + b4.w;
            uint2 pk;
            pk.x = pack_bf16_rne(o.y, o.x);
            pk.y = pack_bf16_rne(o.w, o.z);
            int chunk = k0 >> 3, half = (k0 >> 2) & 1;
            *(uint2*)(tgtPb + ((size_t)(bb * 64 + chunk) * 128 + u) * 8 + half * 4) = pk;
        }
    }
}

// -------- Joint: out[b,t,u,v] = tanh(src[b,t,:]+tgtP[b,u,:]) @ Wl + bl
// bf16 A-frags from tgtPb (2x16B loads/kstep), 2-deep prefetch on A and B.
__global__ __launch_bounds__(256) void joint_mfma(
    const float* __restrict__ src, const unsigned short* __restrict__ tgtPb,
    const unsigned short* __restrict__ Wpl, const float* __restrict__ bl,
    float* __restrict__ out)
{
    __shared__ float srcl[2 * Hh];

    const int t0 = blockIdx.x * 2, b = blockIdx.y, uh = blockIdx.z;
    const int tid = threadIdx.x;
    const int lane = tid & 63, wave = tid >> 6;
    const int ncol = lane & 15, quad = lane >> 4;

    const float4* s4 = (const float4*)(src + ((size_t)(b * Tt + t0)) * Hh);
    ((float4*)srcl)[tid] = s4[tid];

    const int u0 = uh * 64 + (wave & 1) * 32 + ncol;
    const unsigned short* pA = tgtPb + (size_t)b * 65536;
    const unsigned short* bp = Wpl + (size_t)lane * 8;

    uint4 Aa[2], Ac[2];
    short8 Bq[2][3];
    {   // prologue: ks=0,1 in flight
        const unsigned short* p0 = pA + ((size_t)(0 * 4 + quad) * 128) * 8;
        Aa[0] = *(const uint4*)(p0 + u0 * 8);
        Ac[0] = *(const uint4*)(p0 + (u0 + 16) * 8);
        Bq[0][0] = *(const short8*)(bp);
        Bq[0][1] = *(const short8*)(bp + 8192);
        Bq[0][2] = *(const short8*)(bp + 16384);
        const unsigned short* p1 = pA + ((size_t)(1 * 4 + quad) * 128) * 8;
        Aa[1] = *(const uint4*)(p1 + u0 * 8);
        Ac[1] = *(const uint4*)(p1 + (u0 + 16) * 8);
        Bq[1][0] = *(const short8*)(bp + 512);
        Bq[1][1] = *(const short8*)(bp + 8192 + 512);
        Bq[1][2] = *(const short8*)(bp + 16384 + 512);
    }

    f32x4 acc[2][3];
    #pragma unroll
    for (int nt = 0; nt < 3; ++nt) {
        int n = nt * 16 + ncol;
        float bv = (n < Vv) ? bl[n] : 0.0f;
        acc[0][nt] = (f32x4){bv, bv, bv, bv};
        acc[1][nt] = (f32x4){bv, bv, bv, bv};
    }

    __syncthreads();
    const float* srow = srcl + (wave >> 1) * Hh;
    float4 sA = *(const float4*)(srow + quad * 8);
    float4 sB = *(const float4*)(srow + quad * 8 + 4);

    #pragma unroll
    for (int ks = 0; ks < 16; ++ks) {
        const int st = ks & 1;
        uint4 a = Aa[st], c = Ac[st];
        short8 B0 = Bq[st][0], B1 = Bq[st][1], B2 = Bq[st][2];

        if (ks + 2 < 16) {   // refill this stage, 2 ksteps ahead
            const unsigned short* pn = pA + ((size_t)((ks + 2) * 4 + quad) * 128) * 8;
            Aa[st] = *(const uint4*)(pn + u0 * 8);
            Ac[st] = *(const uint4*)(pn + (u0 + 16) * 8);
            Bq[st][0] = *(const short8*)(bp + (ks + 2) * 512);
            Bq[st][1] = *(const short8*)(bp + 8192 + (ks + 2) * 512);
            Bq[st][2] = *(const short8*)(bp + 16384 + (ks + 2) * 512);
        }
        float4 nsA, nsB;
        if (ks < 15) {
            nsA = *(const float4*)(srow + (ks + 1) * 32 + quad * 8);
            nsB = *(const float4*)(srow + (ks + 1) * 32 + quad * 8 + 4);
        }

        union { uint4 u; short8 s; } f0, f1;
        f0.u.x = tanh2_pack(sA.x + bf16lo(a.x), sA.y + bf16hi(a.x));
        f0.u.y = tanh2_pack(sA.z + bf16lo(a.y), sA.w + bf16hi(a.y));
        f0.u.z = tanh2_pack(sB.x + bf16lo(a.z), sB.y + bf16hi(a.z));
        f0.u.w = tanh2_pack(sB.z + bf16lo(a.w), sB.w + bf16hi(a.w));
        f1.u.x = tanh2_pack(sA.x + bf16lo(c.x), sA.y + bf16hi(c.x));
        f1.u.y = tanh2_pack(sA.z + bf16lo(c.y), sA.w + bf16hi(c.y));
        f1.u.z = tanh2_pack(sB.x + bf16lo(c.z), sB.y + bf16hi(c.z));
        f1.u.w = tanh2_pack(sB.z + bf16lo(c.w), sB.w + bf16hi(c.w));

        acc[0][0] = __builtin_amdgcn_mfma_f32_16x16x32_bf16(f0.s, B0, acc[0][0], 0, 0, 0);
        acc[1][0] = __builtin_amdgcn_mfma_f32_16x16x32_bf16(f1.s, B0, acc[1][0], 0, 0, 0);
        acc[0][1] = __builtin_amdgcn_mfma_f32_16x16x32_bf16(f0.s, B1, acc[0][1], 0, 0, 0);
        acc[1][1] = __builtin_amdgcn_mfma_f32_16x16x32_bf16(f1.s, B1, acc[1][1], 0, 0, 0);
        acc[0][2] = __builtin_amdgcn_mfma_f32_16x16x32_bf16(f0.s, B2, acc[0][2], 0, 0, 0);
        acc[1][2] = __builtin_amdgcn_mfma_f32_16x16x32_bf16(f1.s, B2, acc[1][2], 0, 0, 0);

        sA = nsA; sB = nsB;
    }

    // epilogue: C layout col=lane&15, row=quad*4+reg (validated r2-r6)
    const int t = t0 + (wave >> 1);
    const int ub = uh * 64 + (wave & 1) * 32;
    float* ob = out + ((size_t)(b * Tt + t)) * Uu * Vv;
    #pragma unroll
    for (int mi = 0; mi < 2; ++mi) {
        #pragma unroll
        for (int nt = 0; nt < 3; ++nt) {
            int n = nt * 16 + ncol;
            if (n < Vv) {
                #pragma unroll
                for (int r = 0; r < 4; ++r) {
                    int m = ub + mi * 16 + quad * 4 + r;
                    ob[m * Vv + n] = acc[mi][nt][r];
                }
            }
        }
    }
}

extern "C" void kernel_launch(void* const* d_in, const int* in_sizes, int n_in,
                              void* d_out, int out_size, void* d_ws, size_t ws_size,
                              hipStream_t stream)
{
    const float* src  = (const float*)d_in[0];
    const int*   slen = (const int*)  d_in[1];
    const float* tgt  = (const float*)d_in[2];
    const int*   tlen = (const int*)  d_in[3];
    const float* W1   = (const float*)d_in[4];
    const float* b1   = (const float*)d_in[5];
    const float* W2   = (const float*)d_in[6];
    const float* b2   = (const float*)d_in[7];
    const float* ln_g = (const float*)d_in[8];
    const float* ln_b = (const float*)d_in[9];
    const float* Wl   = (const float*)d_in[10];
    const float* bl   = (const float*)d_in[11];

    float* out = (float*)d_out;
    char* ws = (char*)d_ws;
    // ws: tgtPb bf16 512K | Wp1 512K | Wp2 512K | Wpl 64K | tgtA 512K | h1A 512K
    unsigned short* tgtPb = (unsigned short*)(ws);
    unsigned short* Wp1   = (unsigned short*)(ws + 524288);
    unsigned short* Wp2   = (unsigned short*)(ws + 1048576);
    unsigned short* Wpl   = (unsigned short*)(ws + 1572864);
    unsigned short* tgtA  = (unsigned short*)(ws + 1638400);
    unsigned short* h1A   = (unsigned short*)(ws + 2162688);

    hipLaunchKernelGGL(prep_pack, dim3(168), dim3(256), 0, stream,
                       W1, W2, Wl, tgt, Wp1, Wp2, Wpl, tgtA,
                       slen, tlen, out + (size_t)Bb * Tt * Uu * Vv);
    hipLaunchKernelGGL(gemm_t1, dim3(8, 32), dim3(128), 0, stream,
                       tgtA, Wp1, b1, h1A);
    hipLaunchKernelGGL(gemm_t2ln, dim3(32), dim3(512), 0, stream,
                       h1A, Wp2, b2, ln_g, ln_b, tgtPb);
    hipLaunchKernelGGL(joint_mfma, dim3(Tt / 2, Bb, 2), dim3(256), 0, stream,
                       src, tgtPb, Wpl, bl, out);
}

// Round 8
// 142.395 us; speedup vs baseline: 1.0033x; 1.0033x over previous
//
#include <hip/hip_runtime.h>
#include <math.h>

#define Bb 4
#define Tt 512
#define Uu 128
#define Hh 512
#define Vv 41

typedef __attribute__((ext_vector_type(8))) short short8;
typedef __attribute__((ext_vector_type(4))) float f32x4;
typedef __attribute__((ext_vector_type(2))) float v2f;

// RNE bf16 pack of two floats -> u32 [lo | hi<<16]
__device__ __forceinline__ unsigned pack_bf16_rne(float hi, float lo) {
    unsigned xh = __float_as_uint(hi); xh += 0x7fffu + ((xh >> 16) & 1u);
    unsigned xl = __float_as_uint(lo); xl += 0x7fffu + ((xl >> 16) & 1u);
    return __builtin_amdgcn_perm(xh, xl, 0x07060302);
}

__device__ __forceinline__ unsigned short bf16_rne(float v) {
    unsigned x = __float_as_uint(v);
    x += 0x7fffu + ((x >> 16) & 1u);
    return (unsigned short)(x >> 16);
}

// bf16 pair unpack (u32 = [lo | hi<<16])
__device__ __forceinline__ float bf16lo(unsigned u) { return __uint_as_float(u << 16); }
__device__ __forceinline__ float bf16hi(unsigned u) { return __uint_as_float(u & 0xffff0000u); }

// accurate tanh (err ~1e-6): 1 - 2/(e^{2x}+1); saturates correctly.
__device__ __forceinline__ float tanh_acc(float x) {
    float e = __expf(2.0f * x);
    return 1.0f - 2.0f * __builtin_amdgcn_rcpf(e + 1.0f);
}

// EXACT tanh addition: tanh(s+t) = (ts+tt)/(1+ts*tt), given ts=tanh(s), tt=tanh(t).
// aw holds 2 bf16 tt values; ts0/ts1 fp32.  8 inst/pair, no clamps/polys.
__device__ __forceinline__ unsigned mob2(unsigned aw, float ts0, float ts1) {
    v2f tt = {bf16lo(aw), bf16hi(aw)};
    v2f ts = {ts0, ts1};
    v2f nm = ts + tt;                     // v_pk_add_f32
    v2f dn = ts * tt + (v2f){1.f, 1.f};   // v_pk_fma_f32
    v2f g;
    g.x = nm.x * __builtin_amdgcn_rcpf(dn.x);
    g.y = nm.y * __builtin_amdgcn_rcpf(dn.y);
    return __builtin_amdgcn_perm(__float_as_uint(g.y), __float_as_uint(g.x), 0x07060302);
}

// -------- Prep: blocks 0..135: W1,W2,Wl -> MFMA B-frag order
// Wp[ntile][kstep][lane][8 bf16]; block 135 also writes lengths.
// Blocks 136..167: tgt -> A-frag order tgtA[rowtile][kstep][lane][8 bf16].
__global__ __launch_bounds__(256) void prep_pack(
    const float* __restrict__ W1, const float* __restrict__ W2,
    const float* __restrict__ Wl, const float* __restrict__ tgt,
    unsigned short* __restrict__ Wp1, unsigned short* __restrict__ Wp2,
    unsigned short* __restrict__ Wpl, unsigned short* __restrict__ tgtA,
    const int* __restrict__ sl, const int* __restrict__ tl,
    float* __restrict__ lenDst)
{
    __shared__ __align__(16) char smem[16640];
    const int bid = blockIdx.x, tid = threadIdx.x;

    if (bid >= 136) {   // ---- tgt -> A-frag pack
        unsigned short (*At)[520] = (unsigned short (*)[520])smem;
        const int rt = bid - 136;
        const float4* t4 = (const float4*)(tgt + (size_t)rt * 16 * Hh);
        #pragma unroll
        for (int j = 0; j < 8; ++j) {
            int fi = j * 256 + tid;            // 0..2047
            int row = fi >> 7, c4 = fi & 127;
            float4 v = t4[fi];
            uint2 pk;
            pk.x = pack_bf16_rne(v.y, v.x);
            pk.y = pack_bf16_rne(v.w, v.z);
            *(uint2*)&At[row][c4 * 4] = pk;
        }
        __syncthreads();
        #pragma unroll
        for (int i = 0; i < 4; ++i) {
            int chunk = i * 256 + tid;         // 0..1023
            int ks = chunk >> 6, l = chunk & 63;
            int q = l >> 4, nc = l & 15;
            short8 v = *(const short8*)&At[nc][ks * 32 + q * 8];
            *(short8*)(tgtA + ((size_t)(rt * 16 + ks) * 64 + l) * 8) = v;
        }
        return;
    }

    if (bid == 135 && tid < 2 * Bb)
        lenDst[tid] = (tid < Bb) ? (float)sl[tid] : (float)tl[tid - Bb];

    float (*T)[65] = (float (*)[65])smem;
    const float* Wsrc; unsigned short* Wdst; int k0, n0, isWl;
    if (bid < 64)       { Wsrc = W1; Wdst = Wp1; k0 = (bid >> 3) * 64; n0 = (bid & 7) * 64; isWl = 0; }
    else if (bid < 128) { Wsrc = W2; Wdst = Wp2; k0 = ((bid - 64) >> 3) * 64; n0 = ((bid - 64) & 7) * 64; isWl = 0; }
    else                { Wsrc = Wl; Wdst = Wpl; k0 = (bid - 128) * 64; n0 = 0; isWl = 1; }

    #pragma unroll
    for (int i = 0; i < 16; ++i) {
        int idx = i * 256 + tid;
        int kk = idx >> 6, nn = idx & 63;
        float v;
        if (isWl) v = (nn < Vv) ? Wl[(k0 + kk) * Vv + nn] : 0.0f;
        else      v = Wsrc[(size_t)(k0 + kk) * 512 + n0 + nn];
        T[kk][nn] = v;
    }
    __syncthreads();

    #pragma unroll
    for (int i = 0; i < 2; ++i) {
        int task = i * 256 + tid;
        int nn = task & 63, kg = task >> 6;
        if (isWl && nn >= 48) continue;
        int n = n0 + nn, k = k0 + kg * 8;
        float e[8];
        #pragma unroll
        for (int j = 0; j < 8; ++j) e[j] = T[kg * 8 + j][nn];
        uint4 pk;
        pk.x = pack_bf16_rne(e[1], e[0]);
        pk.y = pack_bf16_rne(e[3], e[2]);
        pk.z = pack_bf16_rne(e[5], e[4]);
        pk.w = pack_bf16_rne(e[7], e[6]);
        int ntg = n >> 4, ncol = n & 15;
        int ks = (k >> 5) & 15, quad = (k >> 3) & 3;
        int lane = quad * 16 + ncol;
        *(uint4*)(Wdst + (size_t)((ntg * 16 + ks) * 64 + lane) * 8) = pk;
    }
}

// -------- T1: h1 = gelu(tgt@W1 + b1) -> h1A (A-frag order).
__global__ __launch_bounds__(128) void gemm_t1(
    const unsigned short* __restrict__ tgtA,
    const unsigned short* __restrict__ Wp1, const float* __restrict__ b1,
    unsigned short* __restrict__ h1A)
{
    __shared__ unsigned short At[16][72];
    const int nb = blockIdx.x, rt = blockIdx.y;
    const int tid = threadIdx.x, lane = tid & 63, w = tid >> 6;
    const int ncol = lane & 15, quad = lane >> 4;
    const int nt0 = nb * 4 + w * 2;

    const unsigned short* ap = tgtA + ((size_t)rt * 1024 + lane) * 8;
    const unsigned short* bp = Wp1 + (size_t)lane * 8;

    f32x4 acc0 = (f32x4){0.f,0.f,0.f,0.f}, acc1 = (f32x4){0.f,0.f,0.f,0.f};
    short8 ac  = *(const short8*)(ap);
    short8 b0c = *(const short8*)(bp + (size_t)nt0 * 8192);
    short8 b1c = *(const short8*)(bp + (size_t)(nt0 + 1) * 8192);

    #pragma unroll
    for (int ks = 0; ks < 16; ++ks) {
        short8 an, b0n, b1n;
        if (ks < 15) {
            an  = *(const short8*)(ap + (ks + 1) * 512);
            b0n = *(const short8*)(bp + (size_t)nt0 * 8192 + (ks + 1) * 512);
            b1n = *(const short8*)(bp + (size_t)(nt0 + 1) * 8192 + (ks + 1) * 512);
        }
        acc0 = __builtin_amdgcn_mfma_f32_16x16x32_bf16(ac, b0c, acc0, 0, 0, 0);
        acc1 = __builtin_amdgcn_mfma_f32_16x16x32_bf16(ac, b1c, acc1, 0, 0, 0);
        ac = an; b0c = b0n; b1c = b1n;
    }

    #pragma unroll
    for (int nt = 0; nt < 2; ++nt) {
        int n = nb * 64 + w * 32 + nt * 16 + ncol;
        float bias = b1[n];
        f32x4 A = nt ? acc1 : acc0;
        #pragma unroll
        for (int r = 0; r < 4; ++r) {
            float v = A[r] + bias;
            float g = 0.5f * v * (1.0f + erff(v * 0.70710678118654752f));
            At[quad * 4 + r][w * 32 + nt * 16 + ncol] = bf16_rne(g);
        }
    }
    __syncthreads();

    {
        int l = lane;
        short8 v = *(const short8*)&At[l & 15][w * 32 + (l >> 4) * 8];
        int ksg = nb * 2 + w;
        *(short8*)(h1A + ((size_t)(rt * 16 + ksg) * 64 + l) * 8) = v;
    }
}

// -------- T2+LN fused: h2 = h1@W2+b2; tanh(LN(h2)) -> tgtPb bf16 A-frag
// layout tgtPb[b][k/8 (64)][u (128)][8 bf16].  32 blocks x 512 thr.
__global__ __launch_bounds__(512) void gemm_t2ln(
    const unsigned short* __restrict__ h1A,
    const unsigned short* __restrict__ Wp2, const float* __restrict__ b2,
    const float* __restrict__ ln_g, const float* __restrict__ ln_b,
    unsigned short* __restrict__ tgtPb)
{
    __shared__ float Ct[16][520];
    const int rt = blockIdx.x;
    const int tid = threadIdx.x, lane = tid & 63, w = tid >> 6;
    const int ncol = lane & 15, quad = lane >> 4;
    const int nt0 = w * 4;

    const unsigned short* ap = h1A + ((size_t)rt * 1024 + lane) * 8;
    const unsigned short* bp = Wp2 + (size_t)lane * 8 + (size_t)nt0 * 8192;

    f32x4 acc[4];
    #pragma unroll
    for (int i = 0; i < 4; ++i) acc[i] = (f32x4){0.f, 0.f, 0.f, 0.f};

    short8 ac = *(const short8*)(ap);
    short8 bc[4];
    #pragma unroll
    for (int i = 0; i < 4; ++i) bc[i] = *(const short8*)(bp + (size_t)i * 8192);

    #pragma unroll
    for (int ks = 0; ks < 16; ++ks) {
        short8 an, bn[4];
        if (ks < 15) {
            an = *(const short8*)(ap + (ks + 1) * 512);
            #pragma unroll
            for (int i = 0; i < 4; ++i)
                bn[i] = *(const short8*)(bp + (size_t)i * 8192 + (ks + 1) * 512);
        }
        #pragma unroll
        for (int i = 0; i < 4; ++i)
            acc[i] = __builtin_amdgcn_mfma_f32_16x16x32_bf16(ac, bc[i], acc[i], 0, 0, 0);
        ac = an;
        #pragma unroll
        for (int i = 0; i < 4; ++i) bc[i] = bn[i];
    }

    #pragma unroll
    for (int nt = 0; nt < 4; ++nt) {
        int n = w * 64 + nt * 16 + ncol;
        float bias = b2[n];
        #pragma unroll
        for (int r = 0; r < 4; ++r)
            Ct[quad * 4 + r][n] = acc[nt][r] + bias;
    }
    __syncthreads();

    // LayerNorm + tanh: wave w handles rows 2w, 2w+1; write bf16 A-frag layout
    #pragma unroll
    for (int rr = 0; rr < 2; ++rr) {
        const int row = w * 2 + rr;
        const float4* cr = (const float4*)&Ct[row][0];
        float4 v0 = cr[lane], v1 = cr[lane + 64];
        float s = v0.x + v0.y + v0.z + v0.w + v1.x + v1.y + v1.z + v1.w;
        float q = v0.x*v0.x + v0.y*v0.y + v0.z*v0.z + v0.w*v0.w
                + v1.x*v1.x + v1.y*v1.y + v1.z*v1.z + v1.w*v1.w;
        #pragma unroll
        for (int off = 32; off > 0; off >>= 1) {
            s += __shfl_xor(s, off, 64);
            q += __shfl_xor(q, off, 64);
        }
        float mu = s * (1.0f / Hh);
        float rs = rsqrtf(q * (1.0f / Hh) - mu * mu + 1e-5f);

        const int r = rt * 16 + row;
        const int bb = r >> 7, u = r & 127;
        #pragma unroll
        for (int j = 0; j < 2; ++j) {
            int k0 = j * 256 + lane * 4;       // this lane's 4 k-values
            float4 v = j ? v1 : v0;
            float4 g4 = ((const float4*)ln_g)[j * 64 + lane];
            float4 b4 = ((const float4*)ln_b)[j * 64 + lane];
            float4 o;
            o.x = tanh_acc((v.x - mu) * rs * g4.x + b4.x);
            o.y = tanh_acc((v.y - mu) * rs * g4.y + b4.y);
            o.z = tanh_acc((v.z - mu) * rs * g4.z + b4.z);
            o.w = tanh_acc((v.w - mu) * rs * g4.w + b4.w);
            uint2 pk;
            pk.x = pack_bf16_rne(o.y, o.x);
            pk.y = pack_bf16_rne(o.w, o.z);
            int chunk = k0 >> 3, half = (k0 >> 2) & 1;
            *(uint2*)(tgtPb + ((size_t)(bb * 64 + chunk) * 128 + u) * 8 + half * 4) = pk;
        }
    }
}

// -------- Joint: out = tanh(src+tgtP) @ Wl + bl via EXACT tanh-sum identity:
// srcl holds tanh(src) fp32; tgtPb holds tanh(LN out) bf16 A-frags.
// Inner pair: unpack + pk_add + pk_fma + 2 rcp + pk_mul + perm (8 inst).
__global__ __launch_bounds__(256) void joint_mfma(
    const float* __restrict__ src, const unsigned short* __restrict__ tgtPb,
    const unsigned short* __restrict__ Wpl, const float* __restrict__ bl,
    float* __restrict__ out)
{
    __shared__ float srcl[2 * Hh];

    const int t0 = blockIdx.x * 2, b = blockIdx.y, uh = blockIdx.z;
    const int tid = threadIdx.x;
    const int lane = tid & 63, wave = tid >> 6;
    const int ncol = lane & 15, quad = lane >> 4;

    {   // stage tanh(src) for the two rows
        const float4* s4 = (const float4*)(src + ((size_t)(b * Tt + t0)) * Hh);
        float4 v = s4[tid];
        v.x = tanh_acc(v.x); v.y = tanh_acc(v.y);
        v.z = tanh_acc(v.z); v.w = tanh_acc(v.w);
        ((float4*)srcl)[tid] = v;
    }

    const int u0 = uh * 64 + (wave & 1) * 32 + ncol;
    const unsigned short* pA = tgtPb + (size_t)b * 65536;
    const unsigned short* bp = Wpl + (size_t)lane * 8;

    uint4 Aa[2], Ac[2];
    short8 Bq[2][3];
    {   // prologue: ks=0,1 in flight
        const unsigned short* p0 = pA + ((size_t)(0 * 4 + quad) * 128) * 8;
        Aa[0] = *(const uint4*)(p0 + u0 * 8);
        Ac[0] = *(const uint4*)(p0 + (u0 + 16) * 8);
        Bq[0][0] = *(const short8*)(bp);
        Bq[0][1] = *(const short8*)(bp + 8192);
        Bq[0][2] = *(const short8*)(bp + 16384);
        const unsigned short* p1 = pA + ((size_t)(1 * 4 + quad) * 128) * 8;
        Aa[1] = *(const uint4*)(p1 + u0 * 8);
        Ac[1] = *(const uint4*)(p1 + (u0 + 16) * 8);
        Bq[1][0] = *(const short8*)(bp + 512);
        Bq[1][1] = *(const short8*)(bp + 8192 + 512);
        Bq[1][2] = *(const short8*)(bp + 16384 + 512);
    }

    f32x4 acc[2][3];
    #pragma unroll
    for (int nt = 0; nt < 3; ++nt) {
        int n = nt * 16 + ncol;
        float bv = (n < Vv) ? bl[n] : 0.0f;
        acc[0][nt] = (f32x4){bv, bv, bv, bv};
        acc[1][nt] = (f32x4){bv, bv, bv, bv};
    }

    __syncthreads();
    const float* srow = srcl + (wave >> 1) * Hh;
    float4 sA = *(const float4*)(srow + quad * 8);
    float4 sB = *(const float4*)(srow + quad * 8 + 4);

    #pragma unroll
    for (int ks = 0; ks < 16; ++ks) {
        const int st = ks & 1;
        uint4 a = Aa[st], c = Ac[st];
        short8 B0 = Bq[st][0], B1 = Bq[st][1], B2 = Bq[st][2];

        if (ks + 2 < 16) {   // refill this stage, 2 ksteps ahead
            const unsigned short* pn = pA + ((size_t)((ks + 2) * 4 + quad) * 128) * 8;
            Aa[st] = *(const uint4*)(pn + u0 * 8);
            Ac[st] = *(const uint4*)(pn + (u0 + 16) * 8);
            Bq[st][0] = *(const short8*)(bp + (ks + 2) * 512);
            Bq[st][1] = *(const short8*)(bp + 8192 + (ks + 2) * 512);
            Bq[st][2] = *(const short8*)(bp + 16384 + (ks + 2) * 512);
        }
        float4 nsA, nsB;
        if (ks < 15) {
            nsA = *(const float4*)(srow + (ks + 1) * 32 + quad * 8);
            nsB = *(const float4*)(srow + (ks + 1) * 32 + quad * 8 + 4);
        }

        union { uint4 u; short8 s; } f0, f1;
        f0.u.x = mob2(a.x, sA.x, sA.y);
        f0.u.y = mob2(a.y, sA.z, sA.w);
        f0.u.z = mob2(a.z, sB.x, sB.y);
        f0.u.w = mob2(a.w, sB.z, sB.w);
        f1.u.x = mob2(c.x, sA.x, sA.y);
        f1.u.y = mob2(c.y, sA.z, sA.w);
        f1.u.z = mob2(c.z, sB.x, sB.y);
        f1.u.w = mob2(c.w, sB.z, sB.w);

        acc[0][0] = __builtin_amdgcn_mfma_f32_16x16x32_bf16(f0.s, B0, acc[0][0], 0, 0, 0);
        acc[1][0] = __builtin_amdgcn_mfma_f32_16x16x32_bf16(f1.s, B0, acc[1][0], 0, 0, 0);
        acc[0][1] = __builtin_amdgcn_mfma_f32_16x16x32_bf16(f0.s, B1, acc[0][1], 0, 0, 0);
        acc[1][1] = __builtin_amdgcn_mfma_f32_16x16x32_bf16(f1.s, B1, acc[1][1], 0, 0, 0);
        acc[0][2] = __builtin_amdgcn_mfma_f32_16x16x32_bf16(f0.s, B2, acc[0][2], 0, 0, 0);
        acc[1][2] = __builtin_amdgcn_mfma_f32_16x16x32_bf16(f1.s, B2, acc[1][2], 0, 0, 0);

        sA = nsA; sB = nsB;
    }

    // epilogue: C layout col=lane&15, row=quad*4+reg (validated r2-r7)
    const int t = t0 + (wave >> 1);
    const int ub = uh * 64 + (wave & 1) * 32;
    float* ob = out + ((size_t)(b * Tt + t)) * Uu * Vv;
    #pragma unroll
    for (int mi = 0; mi < 2; ++mi) {
        #pragma unroll
        for (int nt = 0; nt < 3; ++nt) {
            int n = nt * 16 + ncol;
            if (n < Vv) {
                #pragma unroll
                for (int r = 0; r < 4; ++r) {
                    int m = ub + mi * 16 + quad * 4 + r;
                    ob[m * Vv + n] = acc[mi][nt][r];
                }
            }
        }
    }
}

extern "C" void kernel_launch(void* const* d_in, const int* in_sizes, int n_in,
                              void* d_out, int out_size, void* d_ws, size_t ws_size,
                              hipStream_t stream)
{
    const float* src  = (const float*)d_in[0];
    const int*   slen = (const int*)  d_in[1];
    const float* tgt  = (const float*)d_in[2];
    const int*   tlen = (const int*)  d_in[3];
    const float* W1   = (const float*)d_in[4];
    const float* b1   = (const float*)d_in[5];
    const float* W2   = (const float*)d_in[6];
    const float* b2   = (const float*)d_in[7];
    const float* ln_g = (const float*)d_in[8];
    const float* ln_b = (const float*)d_in[9];
    const float* Wl   = (const float*)d_in[10];
    const float* bl   = (const float*)d_in[11];

    float* out = (float*)d_out;
    char* ws = (char*)d_ws;
    // ws: tgtPb bf16 512K | Wp1 512K | Wp2 512K | Wpl 64K | tgtA 512K | h1A 512K
    unsigned short* tgtPb = (unsigned short*)(ws);
    unsigned short* Wp1   = (unsigned short*)(ws + 524288);
    unsigned short* Wp2   = (unsigned short*)(ws + 1048576);
    unsigned short* Wpl   = (unsigned short*)(ws + 1572864);
    unsigned short* tgtA  = (unsigned short*)(ws + 1638400);
    unsigned short* h1A   = (unsigned short*)(ws + 2162688);

    hipLaunchKernelGGL(prep_pack, dim3(168), dim3(256), 0, stream,
                       W1, W2, Wl, tgt, Wp1, Wp2, Wpl, tgtA,
                       slen, tlen, out + (size_t)Bb * Tt * Uu * Vv);
    hipLaunchKernelGGL(gemm_t1, dim3(8, 32), dim3(128), 0, stream,
                       tgtA, Wp1, b1, h1A);
    hipLaunchKernelGGL(gemm_t2ln, dim3(32), dim3(512), 0, stream,
                       h1A, Wp2, b2, ln_g, ln_b, tgtPb);
    hipLaunchKernelGGL(joint_mfma, dim3(Tt / 2, Bb, 2), dim3(256), 0, stream,
                       src, tgtPb, Wpl, bl, out);
}

// Round 9
// 138.265 us; speedup vs baseline: 1.0333x; 1.0299x over previous
//
#include <hip/hip_runtime.h>
#include <math.h>

#define Bb 4
#define Tt 512
#define Uu 128
#define Hh 512
#define Vv 41

typedef __attribute__((ext_vector_type(8))) short short8;
typedef __attribute__((ext_vector_type(4))) float f32x4;
typedef __attribute__((ext_vector_type(2))) float v2f;

// RNE bf16 pack of two floats -> u32 [lo | hi<<16]
__device__ __forceinline__ unsigned pack_bf16_rne(float hi, float lo) {
    unsigned xh = __float_as_uint(hi); xh += 0x7fffu + ((xh >> 16) & 1u);
    unsigned xl = __float_as_uint(lo); xl += 0x7fffu + ((xl >> 16) & 1u);
    return __builtin_amdgcn_perm(xh, xl, 0x07060302);
}

__device__ __forceinline__ unsigned short bf16_rne(float v) {
    unsigned x = __float_as_uint(v);
    x += 0x7fffu + ((x >> 16) & 1u);
    return (unsigned short)(x >> 16);
}

// bf16 pair unpack (u32 = [lo | hi<<16])
__device__ __forceinline__ float bf16lo(unsigned u) { return __uint_as_float(u << 16); }
__device__ __forceinline__ float bf16hi(unsigned u) { return __uint_as_float(u & 0xffff0000u); }

// accurate tanh (err ~1e-6): 1 - 2/(e^{2x}+1); saturates correctly.
__device__ __forceinline__ float tanh_acc(float x) {
    float e = __expf(2.0f * x);
    return 1.0f - 2.0f * __builtin_amdgcn_rcpf(e + 1.0f);
}

// EXACT tanh addition: tanh(s+t) = (ts+tt)/(1+ts*tt).
__device__ __forceinline__ unsigned mob2(unsigned aw, float ts0, float ts1) {
    v2f tt = {bf16lo(aw), bf16hi(aw)};
    v2f ts = {ts0, ts1};
    v2f nm = ts + tt;                     // v_pk_add_f32
    v2f dn = ts * tt + (v2f){1.f, 1.f};   // v_pk_fma_f32
    v2f g;
    g.x = nm.x * __builtin_amdgcn_rcpf(dn.x);
    g.y = nm.y * __builtin_amdgcn_rcpf(dn.y);
    return __builtin_amdgcn_perm(__float_as_uint(g.y), __float_as_uint(g.x), 0x07060302);
}

// -------- Prep: blocks 0..135: W1,W2 -> Wp[ntile][kstep][lane][8 bf16];
// Wl -> Wpl3 [kstep][ntile(3)][lane][8 bf16]  (joint reads 3 B-frags at imm
// offsets 0/1KB/2KB from ONE running pointer).  Block 135 writes lengths.
// Blocks 136..167: tgt -> A-frag order tgtA[rowtile][kstep][lane][8 bf16].
__global__ __launch_bounds__(256) void prep_pack(
    const float* __restrict__ W1, const float* __restrict__ W2,
    const float* __restrict__ Wl, const float* __restrict__ tgt,
    unsigned short* __restrict__ Wp1, unsigned short* __restrict__ Wp2,
    unsigned short* __restrict__ Wpl3, unsigned short* __restrict__ tgtA,
    const int* __restrict__ sl, const int* __restrict__ tl,
    float* __restrict__ lenDst)
{
    __shared__ __align__(16) char smem[16640];
    const int bid = blockIdx.x, tid = threadIdx.x;

    if (bid >= 136) {   // ---- tgt -> A-frag pack
        unsigned short (*At)[520] = (unsigned short (*)[520])smem;
        const int rt = bid - 136;
        const float4* t4 = (const float4*)(tgt + (size_t)rt * 16 * Hh);
        #pragma unroll
        for (int j = 0; j < 8; ++j) {
            int fi = j * 256 + tid;            // 0..2047
            int row = fi >> 7, c4 = fi & 127;
            float4 v = t4[fi];
            uint2 pk;
            pk.x = pack_bf16_rne(v.y, v.x);
            pk.y = pack_bf16_rne(v.w, v.z);
            *(uint2*)&At[row][c4 * 4] = pk;
        }
        __syncthreads();
        #pragma unroll
        for (int i = 0; i < 4; ++i) {
            int chunk = i * 256 + tid;         // 0..1023
            int ks = chunk >> 6, l = chunk & 63;
            int q = l >> 4, nc = l & 15;
            short8 v = *(const short8*)&At[nc][ks * 32 + q * 8];
            *(short8*)(tgtA + ((size_t)(rt * 16 + ks) * 64 + l) * 8) = v;
        }
        return;
    }

    if (bid == 135 && tid < 2 * Bb)
        lenDst[tid] = (tid < Bb) ? (float)sl[tid] : (float)tl[tid - Bb];

    float (*T)[65] = (float (*)[65])smem;
    const float* Wsrc; unsigned short* Wdst; int k0, n0, isWl;
    if (bid < 64)       { Wsrc = W1; Wdst = Wp1; k0 = (bid >> 3) * 64; n0 = (bid & 7) * 64; isWl = 0; }
    else if (bid < 128) { Wsrc = W2; Wdst = Wp2; k0 = ((bid - 64) >> 3) * 64; n0 = ((bid - 64) & 7) * 64; isWl = 0; }
    else                { Wsrc = Wl; Wdst = Wpl3; k0 = (bid - 128) * 64; n0 = 0; isWl = 1; }

    #pragma unroll
    for (int i = 0; i < 16; ++i) {
        int idx = i * 256 + tid;
        int kk = idx >> 6, nn = idx & 63;
        float v;
        if (isWl) v = (nn < Vv) ? Wl[(k0 + kk) * Vv + nn] : 0.0f;
        else      v = Wsrc[(size_t)(k0 + kk) * 512 + n0 + nn];
        T[kk][nn] = v;
    }
    __syncthreads();

    #pragma unroll
    for (int i = 0; i < 2; ++i) {
        int task = i * 256 + tid;
        int nn = task & 63, kg = task >> 6;
        if (isWl && nn >= 48) continue;
        int n = n0 + nn, k = k0 + kg * 8;
        float e[8];
        #pragma unroll
        for (int j = 0; j < 8; ++j) e[j] = T[kg * 8 + j][nn];
        uint4 pk;
        pk.x = pack_bf16_rne(e[1], e[0]);
        pk.y = pack_bf16_rne(e[3], e[2]);
        pk.z = pack_bf16_rne(e[5], e[4]);
        pk.w = pack_bf16_rne(e[7], e[6]);
        int ntg = n >> 4, ncol = n & 15;
        int ks = (k >> 5) & 15, quad = (k >> 3) & 3;
        int lane = quad * 16 + ncol;
        size_t slot = isWl ? (size_t)((ks * 3 + ntg) * 64 + lane)
                           : (size_t)((ntg * 16 + ks) * 64 + lane);
        *(uint4*)(Wdst + slot * 8) = pk;
    }
}

// -------- T1: h1 = gelu(tgt@W1 + b1) -> h1A (A-frag order).
__global__ __launch_bounds__(128) void gemm_t1(
    const unsigned short* __restrict__ tgtA,
    const unsigned short* __restrict__ Wp1, const float* __restrict__ b1,
    unsigned short* __restrict__ h1A)
{
    __shared__ unsigned short At[16][72];
    const int nb = blockIdx.x, rt = blockIdx.y;
    const int tid = threadIdx.x, lane = tid & 63, w = tid >> 6;
    const int ncol = lane & 15, quad = lane >> 4;
    const int nt0 = nb * 4 + w * 2;

    const unsigned short* ap = tgtA + ((size_t)rt * 1024 + lane) * 8;
    const unsigned short* bp = Wp1 + (size_t)lane * 8;

    f32x4 acc0 = (f32x4){0.f,0.f,0.f,0.f}, acc1 = (f32x4){0.f,0.f,0.f,0.f};
    short8 ac  = *(const short8*)(ap);
    short8 b0c = *(const short8*)(bp + (size_t)nt0 * 8192);
    short8 b1c = *(const short8*)(bp + (size_t)(nt0 + 1) * 8192);

    #pragma unroll
    for (int ks = 0; ks < 16; ++ks) {
        short8 an, b0n, b1n;
        if (ks < 15) {
            an  = *(const short8*)(ap + (ks + 1) * 512);
            b0n = *(const short8*)(bp + (size_t)nt0 * 8192 + (ks + 1) * 512);
            b1n = *(const short8*)(bp + (size_t)(nt0 + 1) * 8192 + (ks + 1) * 512);
        }
        acc0 = __builtin_amdgcn_mfma_f32_16x16x32_bf16(ac, b0c, acc0, 0, 0, 0);
        acc1 = __builtin_amdgcn_mfma_f32_16x16x32_bf16(ac, b1c, acc1, 0, 0, 0);
        ac = an; b0c = b0n; b1c = b1n;
    }

    #pragma unroll
    for (int nt = 0; nt < 2; ++nt) {
        int n = nb * 64 + w * 32 + nt * 16 + ncol;
        float bias = b1[n];
        f32x4 A = nt ? acc1 : acc0;
        #pragma unroll
        for (int r = 0; r < 4; ++r) {
            float v = A[r] + bias;
            float g = 0.5f * v * (1.0f + erff(v * 0.70710678118654752f));
            At[quad * 4 + r][w * 32 + nt * 16 + ncol] = bf16_rne(g);
        }
    }
    __syncthreads();

    {
        int l = lane;
        short8 v = *(const short8*)&At[l & 15][w * 32 + (l >> 4) * 8];
        int ksg = nb * 2 + w;
        *(short8*)(h1A + ((size_t)(rt * 16 + ksg) * 64 + l) * 8) = v;
    }
}

// -------- T2+LN fused: h2 = h1@W2+b2; tanh(LN(h2)) -> tgtPb bf16 A-frag
// layout tgtPb[b][k/8 (64)][u (128)][8 bf16].  32 blocks x 512 thr.
__global__ __launch_bounds__(512) void gemm_t2ln(
    const unsigned short* __restrict__ h1A,
    const unsigned short* __restrict__ Wp2, const float* __restrict__ b2,
    const float* __restrict__ ln_g, const float* __restrict__ ln_b,
    unsigned short* __restrict__ tgtPb)
{
    __shared__ float Ct[16][520];
    const int rt = blockIdx.x;
    const int tid = threadIdx.x, lane = tid & 63, w = tid >> 6;
    const int ncol = lane & 15, quad = lane >> 4;
    const int nt0 = w * 4;

    const unsigned short* ap = h1A + ((size_t)rt * 1024 + lane) * 8;
    const unsigned short* bp = Wp2 + (size_t)lane * 8 + (size_t)nt0 * 8192;

    f32x4 acc[4];
    #pragma unroll
    for (int i = 0; i < 4; ++i) acc[i] = (f32x4){0.f, 0.f, 0.f, 0.f};

    short8 ac = *(const short8*)(ap);
    short8 bc[4];
    #pragma unroll
    for (int i = 0; i < 4; ++i) bc[i] = *(const short8*)(bp + (size_t)i * 8192);

    #pragma unroll
    for (int ks = 0; ks < 16; ++ks) {
        short8 an, bn[4];
        if (ks < 15) {
            an = *(const short8*)(ap + (ks + 1) * 512);
            #pragma unroll
            for (int i = 0; i < 4; ++i)
                bn[i] = *(const short8*)(bp + (size_t)i * 8192 + (ks + 1) * 512);
        }
        #pragma unroll
        for (int i = 0; i < 4; ++i)
            acc[i] = __builtin_amdgcn_mfma_f32_16x16x32_bf16(ac, bc[i], acc[i], 0, 0, 0);
        ac = an;
        #pragma unroll
        for (int i = 0; i < 4; ++i) bc[i] = bn[i];
    }

    #pragma unroll
    for (int nt = 0; nt < 4; ++nt) {
        int n = w * 64 + nt * 16 + ncol;
        float bias = b2[n];
        #pragma unroll
        for (int r = 0; r < 4; ++r)
            Ct[quad * 4 + r][n] = acc[nt][r] + bias;
    }
    __syncthreads();

    // LayerNorm + tanh: wave w handles rows 2w, 2w+1; write bf16 A-frag layout
    #pragma unroll
    for (int rr = 0; rr < 2; ++rr) {
        const int row = w * 2 + rr;
        const float4* cr = (const float4*)&Ct[row][0];
        float4 v0 = cr[lane], v1 = cr[lane + 64];
        float s = v0.x + v0.y + v0.z + v0.w + v1.x + v1.y + v1.z + v1.w;
        float q = v0.x*v0.x + v0.y*v0.y + v0.z*v0.z + v0.w*v0.w
                + v1.x*v1.x + v1.y*v1.y + v1.z*v1.z + v1.w*v1.w;
        #pragma unroll
        for (int off = 32; off > 0; off >>= 1) {
            s += __shfl_xor(s, off, 64);
            q += __shfl_xor(q, off, 64);
        }
        float mu = s * (1.0f / Hh);
        float rs = rsqrtf(q * (1.0f / Hh) - mu * mu + 1e-5f);

        const int r = rt * 16 + row;
        const int bb = r >> 7, u = r & 127;
        #pragma unroll
        for (int j = 0; j < 2; ++j) {
            int k0 = j * 256 + lane * 4;       // this lane's 4 k-values
            float4 v = j ? v1 : v0;
            float4 g4 = ((const float4*)ln_g)[j * 64 + lane];
            float4 b4 = ((const float4*)ln_b)[j * 64 + lane];
            float4 o;
            o.x = tanh_acc((v.x - mu) * rs * g4.x + b4.x);
            o.y = tanh_acc((v.y - mu) * rs * g4.y + b4.y);
            o.z = tanh_acc((v.z - mu) * rs * g4.z + b4.z);
            o.w = tanh_acc((v.w - mu) * rs * g4.w + b4.w);
            uint2 pk;
            pk.x = pack_bf16_rne(o.y, o.x);
            pk.y = pack_bf16_rne(o.w, o.z);
            int chunk = k0 >> 3, half = (k0 >> 2) & 1;
            *(uint2*)(tgtPb + ((size_t)(bb * 64 + chunk) * 128 + u) * 8 + half * 4) = pk;
        }
    }
}

// -------- Joint: out = tanh(src+tgtP) @ Wl + bl via exact tanh-sum identity.
// Running-pointer addressing (A += 8KB, B += 3KB per kstep; all frag loads at
// small imm offsets).  Epilogue staged through LDS -> contiguous float4 store.
__global__ __launch_bounds__(256) void joint_mfma(
    const float* __restrict__ src, const unsigned short* __restrict__ tgtPb,
    const unsigned short* __restrict__ Wpl3, const float* __restrict__ bl,
    float* __restrict__ out)
{
    __shared__ float srcl[2 * Hh];                       // 4 KB
    __shared__ __align__(16) float tileC[2 * 64 * Vv];   // 21 KB

    const int t0 = blockIdx.x * 2, b = blockIdx.y, uh = blockIdx.z;
    const int tid = threadIdx.x;
    const int lane = tid & 63, wave = tid >> 6;
    const int ncol = lane & 15, quad = lane >> 4;

    {   // stage tanh(src) for the two rows
        const float4* s4 = (const float4*)(src + ((size_t)(b * Tt + t0)) * Hh);
        float4 v = s4[tid];
        v.x = tanh_acc(v.x); v.y = tanh_acc(v.y);
        v.z = tanh_acc(v.z); v.w = tanh_acc(v.w);
        ((float4*)srcl)[tid] = v;
    }

    const int u0 = uh * 64 + (wave & 1) * 32 + ncol;
    // running pointers (elements): A kstep stride = 4 chunks*128u*8 = 4096; B = 3*512 = 1536
    const unsigned short* apl = tgtPb + (size_t)b * 65536 + ((size_t)quad * 128 + u0) * 8;
    const unsigned short* bpl = Wpl3 + (size_t)lane * 8;

    uint4 Aa[2], Ac[2];
    short8 Bq[2][3];
    Aa[0] = *(const uint4*)(apl);
    Ac[0] = *(const uint4*)(apl + 128);
    Bq[0][0] = *(const short8*)(bpl);
    Bq[0][1] = *(const short8*)(bpl + 512);
    Bq[0][2] = *(const short8*)(bpl + 1024);
    apl += 4096; bpl += 1536;
    Aa[1] = *(const uint4*)(apl);
    Ac[1] = *(const uint4*)(apl + 128);
    Bq[1][0] = *(const short8*)(bpl);
    Bq[1][1] = *(const short8*)(bpl + 512);
    Bq[1][2] = *(const short8*)(bpl + 1024);
    apl += 4096; bpl += 1536;

    f32x4 acc[2][3];
    #pragma unroll
    for (int nt = 0; nt < 3; ++nt) {
        int n = nt * 16 + ncol;
        float bv = (n < Vv) ? bl[n] : 0.0f;
        acc[0][nt] = (f32x4){bv, bv, bv, bv};
        acc[1][nt] = (f32x4){bv, bv, bv, bv};
    }

    __syncthreads();
    const float* srow = srcl + (wave >> 1) * Hh;
    float4 sA = *(const float4*)(srow + quad * 8);
    float4 sB = *(const float4*)(srow + quad * 8 + 4);

    #pragma unroll
    for (int ks = 0; ks < 16; ++ks) {
        const int st = ks & 1;
        uint4 a = Aa[st], c = Ac[st];
        short8 B0 = Bq[st][0], B1 = Bq[st][1], B2 = Bq[st][2];

        if (ks + 2 < 16) {   // refill this stage, 2 ksteps ahead
            Aa[st] = *(const uint4*)(apl);
            Ac[st] = *(const uint4*)(apl + 128);
            Bq[st][0] = *(const short8*)(bpl);
            Bq[st][1] = *(const short8*)(bpl + 512);
            Bq[st][2] = *(const short8*)(bpl + 1024);
            apl += 4096; bpl += 1536;
        }
        float4 nsA, nsB;
        if (ks < 15) {
            nsA = *(const float4*)(srow + (ks + 1) * 32 + quad * 8);
            nsB = *(const float4*)(srow + (ks + 1) * 32 + quad * 8 + 4);
        }

        union { uint4 u; short8 s; } f0, f1;
        f0.u.x = mob2(a.x, sA.x, sA.y);
        f0.u.y = mob2(a.y, sA.z, sA.w);
        f0.u.z = mob2(a.z, sB.x, sB.y);
        f0.u.w = mob2(a.w, sB.z, sB.w);
        f1.u.x = mob2(c.x, sA.x, sA.y);
        f1.u.y = mob2(c.y, sA.z, sA.w);
        f1.u.z = mob2(c.z, sB.x, sB.y);
        f1.u.w = mob2(c.w, sB.z, sB.w);

        acc[0][0] = __builtin_amdgcn_mfma_f32_16x16x32_bf16(f0.s, B0, acc[0][0], 0, 0, 0);
        acc[1][0] = __builtin_amdgcn_mfma_f32_16x16x32_bf16(f1.s, B0, acc[1][0], 0, 0, 0);
        acc[0][1] = __builtin_amdgcn_mfma_f32_16x16x32_bf16(f0.s, B1, acc[0][1], 0, 0, 0);
        acc[1][1] = __builtin_amdgcn_mfma_f32_16x16x32_bf16(f1.s, B1, acc[1][1], 0, 0, 0);
        acc[0][2] = __builtin_amdgcn_mfma_f32_16x16x32_bf16(f0.s, B2, acc[0][2], 0, 0, 0);
        acc[1][2] = __builtin_amdgcn_mfma_f32_16x16x32_bf16(f1.s, B2, acc[1][2], 0, 0, 0);

        sA = nsA; sB = nsB;
    }

    // epilogue: stage C tiles (per-t 64x41 fp32) in LDS, then contiguous store.
    {
        const int tloc = wave >> 1;           // which t this wave computed
        const int ubr = (wave & 1) * 32;      // row base within the 64-u tile
        float* tc = tileC + tloc * (64 * Vv);
        #pragma unroll
        for (int mi = 0; mi < 2; ++mi) {
            #pragma unroll
            for (int nt = 0; nt < 3; ++nt) {
                int n = nt * 16 + ncol;
                if (n < Vv) {
                    #pragma unroll
                    for (int r = 0; r < 4; ++r)
                        tc[(ubr + mi * 16 + quad * 4 + r) * Vv + n] = acc[mi][nt][r];
                }
            }
        }
    }
    __syncthreads();
    {
        // each (t, uh) out region is one contiguous 64*41 span, float4-aligned
        float* ob0 = out + (((size_t)(b * Tt + t0)) * Uu + uh * 64) * Vv;
        float* ob1 = out + (((size_t)(b * Tt + t0 + 1)) * Uu + uh * 64) * Vv;
        const float4* tc4 = (const float4*)tileC;
        #pragma unroll
        for (int i = 0; i < 3; ++i) {
            int idx = i * 256 + tid;          // 0..767, need 0..655
            if (idx < 656) {
                ((float4*)ob0)[idx] = tc4[idx];
                ((float4*)ob1)[idx] = tc4[656 + idx];
            }
        }
    }
}

extern "C" void kernel_launch(void* const* d_in, const int* in_sizes, int n_in,
                              void* d_out, int out_size, void* d_ws, size_t ws_size,
                              hipStream_t stream)
{
    const float* src  = (const float*)d_in[0];
    const int*   slen = (const int*)  d_in[1];
    const float* tgt  = (const float*)d_in[2];
    const int*   tlen = (const int*)  d_in[3];
    const float* W1   = (const float*)d_in[4];
    const float* b1   = (const float*)d_in[5];
    const float* W2   = (const float*)d_in[6];
    const float* b2   = (const float*)d_in[7];
    const float* ln_g = (const float*)d_in[8];
    const float* ln_b = (const float*)d_in[9];
    const float* Wl   = (const float*)d_in[10];
    const float* bl   = (const float*)d_in[11];

    float* out = (float*)d_out;
    char* ws = (char*)d_ws;
    // ws: tgtPb bf16 512K | Wp1 512K | Wp2 512K | Wpl3 64K | tgtA 512K | h1A 512K
    unsigned short* tgtPb = (unsigned short*)(ws);
    unsigned short* Wp1   = (unsigned short*)(ws + 524288);
    unsigned short* Wp2   = (unsigned short*)(ws + 1048576);
    unsigned short* Wpl3  = (unsigned short*)(ws + 1572864);
    unsigned short* tgtA  = (unsigned short*)(ws + 1638400);
    unsigned short* h1A   = (unsigned short*)(ws + 2162688);

    hipLaunchKernelGGL(prep_pack, dim3(168), dim3(256), 0, stream,
                       W1, W2, Wl, tgt, Wp1, Wp2, Wpl3, tgtA,
                       slen, tlen, out + (size_t)Bb * Tt * Uu * Vv);
    hipLaunchKernelGGL(gemm_t1, dim3(8, 32), dim3(128), 0, stream,
                       tgtA, Wp1, b1, h1A);
    hipLaunchKernelGGL(gemm_t2ln, dim3(32), dim3(512), 0, stream,
                       h1A, Wp2, b2, ln_g, ln_b, tgtPb);
    hipLaunchKernelGGL(joint_mfma, dim3(Tt / 2, Bb, 2), dim3(256), 0, stream,
                       src, tgtPb, Wpl3, bl, out);
}

// Round 10
// 135.061 us; speedup vs baseline: 1.0578x; 1.0237x over previous
//
#include <hip/hip_runtime.h>
#include <math.h>

#define Bb 4
#define Tt 512
#define Uu 128
#define Hh 512
#define Vv 41

typedef __attribute__((ext_vector_type(8))) short short8;
typedef __attribute__((ext_vector_type(4))) float f32x4;
typedef __attribute__((ext_vector_type(2))) float v2f;

// RNE bf16 pack of two floats -> u32 [lo | hi<<16]
__device__ __forceinline__ unsigned pack_bf16_rne(float hi, float lo) {
    unsigned xh = __float_as_uint(hi); xh += 0x7fffu + ((xh >> 16) & 1u);
    unsigned xl = __float_as_uint(lo); xl += 0x7fffu + ((xl >> 16) & 1u);
    return __builtin_amdgcn_perm(xh, xl, 0x07060302);
}

__device__ __forceinline__ unsigned short bf16_rne(float v) {
    unsigned x = __float_as_uint(v);
    x += 0x7fffu + ((x >> 16) & 1u);
    return (unsigned short)(x >> 16);
}

// bf16 pair unpack (u32 = [lo | hi<<16])
__device__ __forceinline__ float bf16lo(unsigned u) { return __uint_as_float(u << 16); }
__device__ __forceinline__ float bf16hi(unsigned u) { return __uint_as_float(u & 0xffff0000u); }

// accurate tanh (err ~1e-6): 1 - 2/(e^{2x}+1); saturates correctly.
__device__ __forceinline__ float tanh_acc(float x) {
    float e = __expf(2.0f * x);
    return 1.0f - 2.0f * __builtin_amdgcn_rcpf(e + 1.0f);
}

// EXACT tanh addition: tanh(s+t) = (ts+tt)/(1+ts*tt).
__device__ __forceinline__ unsigned mob2(unsigned aw, float ts0, float ts1) {
    v2f tt = {bf16lo(aw), bf16hi(aw)};
    v2f ts = {ts0, ts1};
    v2f nm = ts + tt;                     // v_pk_add_f32
    v2f dn = ts * tt + (v2f){1.f, 1.f};   // v_pk_fma_f32
    v2f g;
    g.x = nm.x * __builtin_amdgcn_rcpf(dn.x);
    g.y = nm.y * __builtin_amdgcn_rcpf(dn.y);
    return __builtin_amdgcn_perm(__float_as_uint(g.y), __float_as_uint(g.x), 0x07060302);
}

// -------- Prep: blocks 0..135: W1,W2 -> Wp[ntile][kstep][lane][8 bf16];
// Wl -> Wpl3 [kstep][ntile(3)][lane][8 bf16].  Block 135 writes lengths.
// Blocks 136..167: tgt -> A-frag order tgtA[rowtile][kstep][lane][8 bf16].
__global__ __launch_bounds__(256) void prep_pack(
    const float* __restrict__ W1, const float* __restrict__ W2,
    const float* __restrict__ Wl, const float* __restrict__ tgt,
    unsigned short* __restrict__ Wp1, unsigned short* __restrict__ Wp2,
    unsigned short* __restrict__ Wpl3, unsigned short* __restrict__ tgtA,
    const int* __restrict__ sl, const int* __restrict__ tl,
    float* __restrict__ lenDst)
{
    __shared__ __align__(16) char smem[16640];
    const int bid = blockIdx.x, tid = threadIdx.x;

    if (bid >= 136) {   // ---- tgt -> A-frag pack
        unsigned short (*At)[520] = (unsigned short (*)[520])smem;
        const int rt = bid - 136;
        const float4* t4 = (const float4*)(tgt + (size_t)rt * 16 * Hh);
        #pragma unroll
        for (int j = 0; j < 8; ++j) {
            int fi = j * 256 + tid;            // 0..2047
            int row = fi >> 7, c4 = fi & 127;
            float4 v = t4[fi];
            uint2 pk;
            pk.x = pack_bf16_rne(v.y, v.x);
            pk.y = pack_bf16_rne(v.w, v.z);
            *(uint2*)&At[row][c4 * 4] = pk;
        }
        __syncthreads();
        #pragma unroll
        for (int i = 0; i < 4; ++i) {
            int chunk = i * 256 + tid;         // 0..1023
            int ks = chunk >> 6, l = chunk & 63;
            int q = l >> 4, nc = l & 15;
            short8 v = *(const short8*)&At[nc][ks * 32 + q * 8];
            *(short8*)(tgtA + ((size_t)(rt * 16 + ks) * 64 + l) * 8) = v;
        }
        return;
    }

    if (bid == 135 && tid < 2 * Bb)
        lenDst[tid] = (tid < Bb) ? (float)sl[tid] : (float)tl[tid - Bb];

    float (*T)[65] = (float (*)[65])smem;
    const float* Wsrc; unsigned short* Wdst; int k0, n0, isWl;
    if (bid < 64)       { Wsrc = W1; Wdst = Wp1; k0 = (bid >> 3) * 64; n0 = (bid & 7) * 64; isWl = 0; }
    else if (bid < 128) { Wsrc = W2; Wdst = Wp2; k0 = ((bid - 64) >> 3) * 64; n0 = ((bid - 64) & 7) * 64; isWl = 0; }
    else                { Wsrc = Wl; Wdst = Wpl3; k0 = (bid - 128) * 64; n0 = 0; isWl = 1; }

    #pragma unroll
    for (int i = 0; i < 16; ++i) {
        int idx = i * 256 + tid;
        int kk = idx >> 6, nn = idx & 63;
        float v;
        if (isWl) v = (nn < Vv) ? Wl[(k0 + kk) * Vv + nn] : 0.0f;
        else      v = Wsrc[(size_t)(k0 + kk) * 512 + n0 + nn];
        T[kk][nn] = v;
    }
    __syncthreads();

    #pragma unroll
    for (int i = 0; i < 2; ++i) {
        int task = i * 256 + tid;
        int nn = task & 63, kg = task >> 6;
        if (isWl && nn >= 48) continue;
        int n = n0 + nn, k = k0 + kg * 8;
        float e[8];
        #pragma unroll
        for (int j = 0; j < 8; ++j) e[j] = T[kg * 8 + j][nn];
        uint4 pk;
        pk.x = pack_bf16_rne(e[1], e[0]);
        pk.y = pack_bf16_rne(e[3], e[2]);
        pk.z = pack_bf16_rne(e[5], e[4]);
        pk.w = pack_bf16_rne(e[7], e[6]);
        int ntg = n >> 4, ncol = n & 15;
        int ks = (k >> 5) & 15, quad = (k >> 3) & 3;
        int lane = quad * 16 + ncol;
        size_t slot = isWl ? (size_t)((ks * 3 + ntg) * 64 + lane)
                           : (size_t)((ntg * 16 + ks) * 64 + lane);
        *(uint4*)(Wdst + slot * 8) = pk;
    }
}

// -------- Target path, fully fused: tanh(LN(gelu(tgt@W1+b1)@W2+b2)) -> tgtPb.
// 32 blocks x 512 thr (8 waves, wave owns 64 n-cols).  Phase 1: GEMM1 from
// tgtA/Wp1 frags -> GELU -> h1 in LDS.  Phase 2: GEMM2 from LDS A / Wp2 ->
// LN+tanh -> tgtPb bf16 A-frag layout [b][k/8][u][8].
__global__ __launch_bounds__(512) void target_fused(
    const unsigned short* __restrict__ tgtA,
    const unsigned short* __restrict__ Wp1, const float* __restrict__ b1,
    const unsigned short* __restrict__ Wp2, const float* __restrict__ b2,
    const float* __restrict__ ln_g, const float* __restrict__ ln_b,
    unsigned short* __restrict__ tgtPb)
{
    __shared__ unsigned short At[16][520];   // h1 bf16 (1040B stride: 2-way max, free)
    __shared__ float Ct[16][520];

    const int rt = blockIdx.x;               // rows rt*16 .. +16
    const int tid = threadIdx.x, lane = tid & 63, w = tid >> 6;
    const int ncol = lane & 15, quad = lane >> 4;

    const unsigned short* ap = tgtA + ((size_t)rt * 1024 + lane) * 8;
    const unsigned short* bp1 = Wp1 + (size_t)lane * 8 + (size_t)(w * 4) * 8192;
    const unsigned short* bp2 = Wp2 + (size_t)lane * 8 + (size_t)(w * 4) * 8192;

    f32x4 acc[4];
    #pragma unroll
    for (int i = 0; i < 4; ++i) acc[i] = (f32x4){0.f, 0.f, 0.f, 0.f};

    {   // Phase 1: GEMM1 (A global frags, B Wp1), double-buffered
        short8 ac = *(const short8*)(ap);
        short8 bc[4];
        #pragma unroll
        for (int i = 0; i < 4; ++i) bc[i] = *(const short8*)(bp1 + (size_t)i * 8192);
        #pragma unroll
        for (int ks = 0; ks < 16; ++ks) {
            short8 an, bn[4];
            if (ks < 15) {
                an = *(const short8*)(ap + (ks + 1) * 512);
                #pragma unroll
                for (int i = 0; i < 4; ++i)
                    bn[i] = *(const short8*)(bp1 + (size_t)i * 8192 + (ks + 1) * 512);
            }
            #pragma unroll
            for (int i = 0; i < 4; ++i)
                acc[i] = __builtin_amdgcn_mfma_f32_16x16x32_bf16(ac, bc[i], acc[i], 0, 0, 0);
            ac = an;
            #pragma unroll
            for (int i = 0; i < 4; ++i) bc[i] = bn[i];
        }
    }

    // GELU(+b1) -> At
    #pragma unroll
    for (int nt = 0; nt < 4; ++nt) {
        int n = w * 64 + nt * 16 + ncol;
        float bias = b1[n];
        #pragma unroll
        for (int r = 0; r < 4; ++r) {
            float v = acc[nt][r] + bias;
            float g = 0.5f * v * (1.0f + erff(v * 0.70710678118654752f));
            At[quad * 4 + r][n] = bf16_rne(g);
        }
        acc[nt] = (f32x4){0.f, 0.f, 0.f, 0.f};
    }
    __syncthreads();

    {   // Phase 2: GEMM2 (A from LDS, B Wp2), B double-buffered
        short8 bc[4];
        #pragma unroll
        for (int i = 0; i < 4; ++i) bc[i] = *(const short8*)(bp2 + (size_t)i * 8192);
        #pragma unroll
        for (int ks = 0; ks < 16; ++ks) {
            short8 bn[4];
            if (ks < 15) {
                #pragma unroll
                for (int i = 0; i < 4; ++i)
                    bn[i] = *(const short8*)(bp2 + (size_t)i * 8192 + (ks + 1) * 512);
            }
            short8 af = *(const short8*)&At[ncol][ks * 32 + quad * 8];
            #pragma unroll
            for (int i = 0; i < 4; ++i)
                acc[i] = __builtin_amdgcn_mfma_f32_16x16x32_bf16(af, bc[i], acc[i], 0, 0, 0);
            #pragma unroll
            for (int i = 0; i < 4; ++i) bc[i] = bn[i];
        }
    }

    #pragma unroll
    for (int nt = 0; nt < 4; ++nt) {
        int n = w * 64 + nt * 16 + ncol;
        float bias = b2[n];
        #pragma unroll
        for (int r = 0; r < 4; ++r)
            Ct[quad * 4 + r][n] = acc[nt][r] + bias;
    }
    __syncthreads();

    // LayerNorm + tanh: wave w handles rows 2w, 2w+1; write bf16 A-frag layout
    #pragma unroll
    for (int rr = 0; rr < 2; ++rr) {
        const int row = w * 2 + rr;
        const float4* cr = (const float4*)&Ct[row][0];
        float4 v0 = cr[lane], v1 = cr[lane + 64];
        float s = v0.x + v0.y + v0.z + v0.w + v1.x + v1.y + v1.z + v1.w;
        float q = v0.x*v0.x + v0.y*v0.y + v0.z*v0.z + v0.w*v0.w
                + v1.x*v1.x + v1.y*v1.y + v1.z*v1.z + v1.w*v1.w;
        #pragma unroll
        for (int off = 32; off > 0; off >>= 1) {
            s += __shfl_xor(s, off, 64);
            q += __shfl_xor(q, off, 64);
        }
        float mu = s * (1.0f / Hh);
        float rs = rsqrtf(q * (1.0f / Hh) - mu * mu + 1e-5f);

        const int r = rt * 16 + row;
        const int bb = r >> 7, u = r & 127;
        #pragma unroll
        for (int j = 0; j < 2; ++j) {
            int k0 = j * 256 + lane * 4;       // this lane's 4 k-values
            float4 v = j ? v1 : v0;
            float4 g4 = ((const float4*)ln_g)[j * 64 + lane];
            float4 b4 = ((const float4*)ln_b)[j * 64 + lane];
            float4 o;
            o.x = tanh_acc((v.x - mu) * rs * g4.x + b4.x);
            o.y = tanh_acc((v.y - mu) * rs * g4.y + b4.y);
            o.z = tanh_acc((v.z - mu) * rs * g4.z + b4.z);
            o.w = tanh_acc((v.w - mu) * rs * g4.w + b4.w);
            uint2 pk;
            pk.x = pack_bf16_rne(o.y, o.x);
            pk.y = pack_bf16_rne(o.w, o.z);
            int chunk = k0 >> 3, half = (k0 >> 2) & 1;
            *(uint2*)(tgtPb + ((size_t)(bb * 64 + chunk) * 128 + u) * 8 + half * 4) = pk;
        }
    }
}

// -------- Joint: out = tanh(src+tgtP) @ Wl + bl via exact tanh-sum identity.
// A-DEDUP: wave = 16 u-rows x BOTH t's: one tt load per kstep feeds two
// Moebius A-frags (t0,t1) -> A L2 traffic halved vs r9.  Running pointers,
// 2-deep prefetch, LDS-staged contiguous epilogue.
__global__ __launch_bounds__(256) void joint_mfma(
    const float* __restrict__ src, const unsigned short* __restrict__ tgtPb,
    const unsigned short* __restrict__ Wpl3, const float* __restrict__ bl,
    float* __restrict__ out)
{
    __shared__ float srcl[2 * Hh];                       // tanh(src) t0,t1 (4 KB)
    __shared__ __align__(16) float tileC[2 * 64 * Vv];   // 21 KB

    const int t0 = blockIdx.x * 2, b = blockIdx.y, uh = blockIdx.z;
    const int tid = threadIdx.x;
    const int lane = tid & 63, wave = tid >> 6;
    const int ncol = lane & 15, quad = lane >> 4;

    {   // stage tanh(src) for the two rows
        const float4* s4 = (const float4*)(src + ((size_t)(b * Tt + t0)) * Hh);
        float4 v = s4[tid];
        v.x = tanh_acc(v.x); v.y = tanh_acc(v.y);
        v.z = tanh_acc(v.z); v.w = tanh_acc(v.w);
        ((float4*)srcl)[tid] = v;
    }

    const int u0 = uh * 64 + wave * 16 + ncol;   // this wave's 16 u-rows
    // running pointers: A kstep stride 4096 elems, B 1536 elems
    const unsigned short* apl = tgtPb + (size_t)b * 65536 + ((size_t)quad * 128 + u0) * 8;
    const unsigned short* bpl = Wpl3 + (size_t)lane * 8;

    uint4 Aq[2];
    short8 Bq[2][3];
    Aq[0] = *(const uint4*)(apl);
    Bq[0][0] = *(const short8*)(bpl);
    Bq[0][1] = *(const short8*)(bpl + 512);
    Bq[0][2] = *(const short8*)(bpl + 1024);
    apl += 4096; bpl += 1536;
    Aq[1] = *(const uint4*)(apl);
    Bq[1][0] = *(const short8*)(bpl);
    Bq[1][1] = *(const short8*)(bpl + 512);
    Bq[1][2] = *(const short8*)(bpl + 1024);
    apl += 4096; bpl += 1536;

    f32x4 acc[2][3];   // [t][ntile]
    #pragma unroll
    for (int nt = 0; nt < 3; ++nt) {
        int n = nt * 16 + ncol;
        float bv = (n < Vv) ? bl[n] : 0.0f;
        acc[0][nt] = (f32x4){bv, bv, bv, bv};
        acc[1][nt] = (f32x4){bv, bv, bv, bv};
    }

    __syncthreads();
    const float* sr0 = srcl;
    const float* sr1 = srcl + Hh;
    float4 sA0 = *(const float4*)(sr0 + quad * 8);
    float4 sB0 = *(const float4*)(sr0 + quad * 8 + 4);
    float4 sA1 = *(const float4*)(sr1 + quad * 8);
    float4 sB1 = *(const float4*)(sr1 + quad * 8 + 4);

    #pragma unroll
    for (int ks = 0; ks < 16; ++ks) {
        const int st = ks & 1;
        uint4 a = Aq[st];
        short8 B0 = Bq[st][0], B1 = Bq[st][1], B2 = Bq[st][2];

        if (ks + 2 < 16) {   // refill this stage, 2 ksteps ahead
            Aq[st] = *(const uint4*)(apl);
            Bq[st][0] = *(const short8*)(bpl);
            Bq[st][1] = *(const short8*)(bpl + 512);
            Bq[st][2] = *(const short8*)(bpl + 1024);
            apl += 4096; bpl += 1536;
        }
        float4 nsA0, nsB0, nsA1, nsB1;
        if (ks < 15) {
            const int o = (ks + 1) * 32 + quad * 8;
            nsA0 = *(const float4*)(sr0 + o);
            nsB0 = *(const float4*)(sr0 + o + 4);
            nsA1 = *(const float4*)(sr1 + o);
            nsB1 = *(const float4*)(sr1 + o + 4);
        }

        union { uint4 u; short8 s; } f0, f1;
        f0.u.x = mob2(a.x, sA0.x, sA0.y);
        f0.u.y = mob2(a.y, sA0.z, sA0.w);
        f0.u.z = mob2(a.z, sB0.x, sB0.y);
        f0.u.w = mob2(a.w, sB0.z, sB0.w);
        f1.u.x = mob2(a.x, sA1.x, sA1.y);
        f1.u.y = mob2(a.y, sA1.z, sA1.w);
        f1.u.z = mob2(a.z, sB1.x, sB1.y);
        f1.u.w = mob2(a.w, sB1.z, sB1.w);

        acc[0][0] = __builtin_amdgcn_mfma_f32_16x16x32_bf16(f0.s, B0, acc[0][0], 0, 0, 0);
        acc[1][0] = __builtin_amdgcn_mfma_f32_16x16x32_bf16(f1.s, B0, acc[1][0], 0, 0, 0);
        acc[0][1] = __builtin_amdgcn_mfma_f32_16x16x32_bf16(f0.s, B1, acc[0][1], 0, 0, 0);
        acc[1][1] = __builtin_amdgcn_mfma_f32_16x16x32_bf16(f1.s, B1, acc[1][1], 0, 0, 0);
        acc[0][2] = __builtin_amdgcn_mfma_f32_16x16x32_bf16(f0.s, B2, acc[0][2], 0, 0, 0);
        acc[1][2] = __builtin_amdgcn_mfma_f32_16x16x32_bf16(f1.s, B2, acc[1][2], 0, 0, 0);

        sA0 = nsA0; sB0 = nsB0; sA1 = nsA1; sB1 = nsB1;
    }

    // epilogue: stage C tiles in LDS (C layout col=lane&15, row=quad*4+reg),
    // then contiguous float4 dump.
    #pragma unroll
    for (int t = 0; t < 2; ++t) {
        float* tc = tileC + t * (64 * Vv);
        #pragma unroll
        for (int nt = 0; nt < 3; ++nt) {
            int n = nt * 16 + ncol;
            if (n < Vv) {
                #pragma unroll
                for (int r = 0; r < 4; ++r)
                    tc[(wave * 16 + quad * 4 + r) * Vv + n] = acc[t][nt][r];
            }
        }
    }
    __syncthreads();
    {
        float* ob0 = out + (((size_t)(b * Tt + t0)) * Uu + uh * 64) * Vv;
        float* ob1 = out + (((size_t)(b * Tt + t0 + 1)) * Uu + uh * 64) * Vv;
        const float4* tc4 = (const float4*)tileC;
        #pragma unroll
        for (int i = 0; i < 3; ++i) {
            int idx = i * 256 + tid;          // need 0..655 per t
            if (idx < 656) {
                ((float4*)ob0)[idx] = tc4[idx];
                ((float4*)ob1)[idx] = tc4[656 + idx];
            }
        }
    }
}

extern "C" void kernel_launch(void* const* d_in, const int* in_sizes, int n_in,
                              void* d_out, int out_size, void* d_ws, size_t ws_size,
                              hipStream_t stream)
{
    const float* src  = (const float*)d_in[0];
    const int*   slen = (const int*)  d_in[1];
    const float* tgt  = (const float*)d_in[2];
    const int*   tlen = (const int*)  d_in[3];
    const float* W1   = (const float*)d_in[4];
    const float* b1   = (const float*)d_in[5];
    const float* W2   = (const float*)d_in[6];
    const float* b2   = (const float*)d_in[7];
    const float* ln_g = (const float*)d_in[8];
    const float* ln_b = (const float*)d_in[9];
    const float* Wl   = (const float*)d_in[10];
    const float* bl   = (const float*)d_in[11];

    float* out = (float*)d_out;
    char* ws = (char*)d_ws;
    // ws: tgtPb bf16 512K | Wp1 512K | Wp2 512K | Wpl3 64K | tgtA 512K
    unsigned short* tgtPb = (unsigned short*)(ws);
    unsigned short* Wp1   = (unsigned short*)(ws + 524288);
    unsigned short* Wp2   = (unsigned short*)(ws + 1048576);
    unsigned short* Wpl3  = (unsigned short*)(ws + 1572864);
    unsigned short* tgtA  = (unsigned short*)(ws + 1638400);

    hipLaunchKernelGGL(prep_pack, dim3(168), dim3(256), 0, stream,
                       W1, W2, Wl, tgt, Wp1, Wp2, Wpl3, tgtA,
                       slen, tlen, out + (size_t)Bb * Tt * Uu * Vv);
    hipLaunchKernelGGL(target_fused, dim3(32), dim3(512), 0, stream,
                       tgtA, Wp1, b1, Wp2, b2, ln_g, ln_b, tgtPb);
    hipLaunchKernelGGL(joint_mfma, dim3(Tt / 2, Bb, 2), dim3(256), 0, stream,
                       src, tgtPb, Wpl3, bl, out);
}